// Round 6
// baseline (1685.568 us; speedup 1.0000x reference)
//
#include <hip/hip_runtime.h>

// ---------------------------------------------------------------------------
// VQ-VAE encoder + vector quantizer, fp32 end-to-end (no MFMA: argmin is a
// discrete decision; bf16 noise would flip indices vs the fp32 reference).
//
//   k_prep : eT[k][d] = emb[d][k];  c[k] = ||e_k||^2
//   k_conv1: 4x4 s2 SAME, 3->32, relu   (weights via wave-uniform s_loads)
//   k_conv2: 4x4 s2 SAME, 32->64, relu  (LDS-tiled implicit GEMM)
//   k_vq   : all-register conv3+VQ (z[128] in VGPRs, codebook via uniform
//            scalar-broadcast loads, no LDS).
//
// r6 FIX vs r4/r5: the output gather copied only 8 float4s (32 floats) of
// the 128-float codebook row -> 3/4 of every output pixel was left at the
// harness's memset(0), absmax == codebook scale 0.05. The distances/argmin
// were never wrong (r4 and r5, with different chain shapes, failed with
// bit-identical absmax). Gather now copies all 32 float4s.
//
// Batch-chunked: the 64 images are processed in `nchunk` chunks so the h1/h2
// intermediates fit whatever ws_size the harness provides. Launch schedule is
// a pure function of ws_size -> identical work every call (graph-capture safe).
// ---------------------------------------------------------------------------

__device__ __forceinline__ float fget(const float4& v, int i) {
    return reinterpret_cast<const float*>(&v)[i];
}

// ---- K0: codebook prep --------------------------------------------------
__global__ void k_prep(const float* __restrict__ emb,
                       float* __restrict__ eT, float* __restrict__ cvec) {
    int k = blockIdx.x * 256 + threadIdx.x;   // 512 threads total
    float s = 0.f;
    #pragma unroll 8
    for (int d = 0; d < 128; ++d) {
        float v = emb[d * 512 + k];           // coalesced (consecutive k)
        s += v * v;
        eT[k * 128 + d] = v;
    }
    cvec[k] = s;
}

// ---- K1: conv1 + relu ---------------------------------------------------
// thread = one output pixel, all 32 channels. Weight indices are wave-uniform
// -> compiler emits s_load; weights live in SGPRs, FMAs take SGPR operand.
__global__ __launch_bounds__(256) void k_conv1(
        const float* __restrict__ x, const float* __restrict__ w1,
        const float* __restrict__ b1, float* __restrict__ h1, int b0) {
    int t = threadIdx.x;
    int p = blockIdx.x * 256 + t;             // chunk-local pixel id
    int ow = p & 127, oh = (p >> 7) & 127, b = b0 + (p >> 14);
    float acc[32];
    #pragma unroll
    for (int c = 0; c < 32; ++c) acc[c] = b1[c];     // uniform scalar loads
    #pragma unroll
    for (int kh = 0; kh < 4; ++kh) {
        int ih = oh * 2 - 1 + kh;                    // SAME pad_lo = 1
        if ((unsigned)ih >= 256u) continue;
        #pragma unroll
        for (int kw = 0; kw < 4; ++kw) {
            int iw = ow * 2 - 1 + kw;
            if ((unsigned)iw >= 256u) continue;
            const float* xp = x + (((size_t)(b * 256 + ih) * 256 + iw) * 3);
            float x0 = xp[0], x1 = xp[1], x2 = xp[2];
            const float* wp = w1 + (kh * 4 + kw) * 96;  // [ci][32c], uniform
            #pragma unroll
            for (int c = 0; c < 32; ++c)
                acc[c] += x0 * wp[c] + x1 * wp[32 + c] + x2 * wp[64 + c];
        }
    }
    float4* op = (float4*)(h1 + (size_t)p * 32);  // thread writes 1 cache line
    #pragma unroll
    for (int c4 = 0; c4 < 8; ++c4) {
        float4 v;
        v.x = fmaxf(acc[c4 * 4 + 0], 0.f);
        v.y = fmaxf(acc[c4 * 4 + 1], 0.f);
        v.z = fmaxf(acc[c4 * 4 + 2], 0.f);
        v.w = fmaxf(acc[c4 * 4 + 3], 0.f);
        op[c4] = v;
    }
}

// ---- K2: conv2 + relu (implicit GEMM, LDS-tiled) ------------------------
// block: 8x8 output pixels x 64 ch for one image. x-tile 18x18x32 in LDS
// (row padded to 580 floats -> 4-row stride = 2320 % 32 = 16 -> 2-way, free).
// weights staged per-kh (32KB). thread (tr,tc): tr->4 px (swizzled so in-wave
// groups differ in ROW), tc->4 cout. 64 FMA per 8 ds_read_b128.
#define XROW 580
__global__ __launch_bounds__(256) void k_conv2(
        const float* __restrict__ h1, const float* __restrict__ w2,
        const float* __restrict__ b2, float* __restrict__ h2) {
    __shared__ float xl[18 * XROW];     // 41.76 KB
    __shared__ float wl[8192];          // 32 KB  (one kh slice: [kw][ci][co])
    __shared__ float bl[64];
    int t = threadIdx.x;
    int blk = blockIdx.x;
    int tx = blk & 7, ty = (blk >> 3) & 7, b = blk >> 6;   // b = chunk-local
    int oh0 = ty * 8, ow0 = tx * 8;
    int ih0 = oh0 * 2 - 1, iw0 = ow0 * 2 - 1;
    if (t < 64) bl[t] = b2[t];
    // stage x tile: 18x18 positions x 8 float4 of channels
    for (int i = t; i < 2592; i += 256) {
        int f = i & 7;
        int pos = i >> 3;
        int r = pos / 18, c = pos - r * 18;
        int ih = ih0 + r, iw = iw0 + c;
        float4 v = make_float4(0.f, 0.f, 0.f, 0.f);
        if ((unsigned)ih < 128u && (unsigned)iw < 128u)
            v = *(const float4*)(h1 + ((size_t)((b * 128 + ih) * 128 + iw) * 32 + f * 4));
        *(float4*)(xl + r * XROW + c * 32 + f * 4) = v;
    }
    int tc = t & 15, tr = t >> 4;
    int g = ((tr & 3) << 2) | (tr >> 2);   // in-wave groups span different rows
    int olr = g >> 1, olc0 = (g & 1) * 4;
    __syncthreads();
    float4 bv = ((const float4*)bl)[tc];
    float4 acc[4];
    #pragma unroll
    for (int j = 0; j < 4; ++j) acc[j] = bv;
    for (int kh = 0; kh < 4; ++kh) {
        __syncthreads();                               // prev wl reads done
        const float4* wsrc = (const float4*)(w2 + kh * 8192);
        for (int i = t; i < 2048; i += 256) ((float4*)wl)[i] = wsrc[i];
        __syncthreads();
        #pragma unroll
        for (int kw = 0; kw < 4; ++kw) {
            #pragma unroll
            for (int ci4 = 0; ci4 < 8; ++ci4) {
                float4 xq[4], wq[4];
                #pragma unroll
                for (int j = 0; j < 4; ++j)
                    xq[j] = *(const float4*)(xl + (olr * 2 + kh) * XROW +
                                             ((olc0 + j) * 2 + kw) * 32 + ci4 * 4);
                #pragma unroll
                for (int i = 0; i < 4; ++i)
                    wq[i] = ((const float4*)wl)[(kw * 32 + ci4 * 4 + i) * 16 + tc];
                #pragma unroll
                for (int i = 0; i < 4; ++i) {
                    #pragma unroll
                    for (int j = 0; j < 4; ++j) {
                        float xv = fget(xq[j], i);
                        acc[j].x += xv * wq[i].x;
                        acc[j].y += xv * wq[i].y;
                        acc[j].z += xv * wq[i].z;
                        acc[j].w += xv * wq[i].w;
                    }
                }
            }
        }
    }
    int oh = oh0 + olr;
    #pragma unroll
    for (int j = 0; j < 4; ++j) {
        int ow = ow0 + olc0 + j;
        float4 v = acc[j];
        v.x = fmaxf(v.x, 0.f); v.y = fmaxf(v.y, 0.f);
        v.z = fmaxf(v.z, 0.f); v.w = fmaxf(v.w, 0.f);
        *(float4*)(h2 + ((size_t)((b * 64 + oh) * 64 + ow) * 64 + tc * 4)) = v;
    }
}

// ---- K3: conv3(1x1) + VQ argmin + gather, all-register ------------------
// thread = 1 pixel. z[128] in VGPRs; w3/b3/eT/cvec read with wave-uniform
// indices -> scalar (SGPR-broadcast) loads; FMAs are v_fmac_f32 with one
// SGPR operand. No LDS.
//   z[d]  = b3[d] + sum_{ci ascending} h[ci]*w3[ci][d]     (one fma chain)
//   s_k   = sum_{d ascending} z[d]*eT[k][d]                (one fma chain)
//   dist  = cvec[k] - 2.f*s_k        (||z||^2 constant, drops under argmin)
// Selection: ascending-k strict '<' = global first-min (jnp.argmin).
__global__ __launch_bounds__(256, 3) void k_vq(
        const float* __restrict__ h2, const float* __restrict__ w3,
        const float* __restrict__ b3, const float* __restrict__ eT,
        const float* __restrict__ cvec, float* __restrict__ out,
        long long px_base) {
    int p = blockIdx.x * 256 + threadIdx.x;   // chunk-local pixel
    const float* h2row = h2 + (size_t)p * 64;

    // ---- phase A: z = w3^T . h2row + b3 (z stays in registers) ----
    float z[128];
    #pragma unroll
    for (int d = 0; d < 128; ++d) z[d] = b3[d];        // uniform -> s_load
    for (int ci = 0; ci < 64; ci += 4) {
        float4 hv = *(const float4*)(h2row + ci);      // per-thread load
        const float* w0 = w3 + ci * 128;
        #pragma unroll
        for (int j = 0; j < 4; ++j) {
            float h = fget(hv, j);
            const float* wr = w0 + j * 128;            // uniform row
            #pragma unroll
            for (int d = 0; d < 128; ++d) z[d] += h * wr[d];
        }
    }

    // ---- phase B: argmin_k ( ||e_k||^2 - 2 z.e_k ) ----
    // ILP across 4 independent codes; each code's dot is ONE ascending chain.
    float minv = 3.4e38f;
    int mini = 0;
    for (int k = 0; k < 512; k += 4) {
        const float* e0 = eT + (size_t)k * 128;        // uniform rows
        const float* e1 = e0 + 128;
        const float* e2 = e0 + 256;
        const float* e3 = e0 + 384;
        float s0 = 0.f, s1 = 0.f, s2 = 0.f, s3 = 0.f;
        #pragma unroll
        for (int d = 0; d < 128; ++d) {
            s0 += z[d] * e0[d];
            s1 += z[d] * e1[d];
            s2 += z[d] * e2[d];
            s3 += z[d] * e3[d];
        }
        float d0 = cvec[k + 0] - 2.f * s0;
        float d1 = cvec[k + 1] - 2.f * s1;
        float d2 = cvec[k + 2] - 2.f * s2;
        float d3 = cvec[k + 3] - 2.f * s3;
        if (d0 < minv) { minv = d0; mini = k + 0; }
        if (d1 < minv) { minv = d1; mini = k + 1; }
        if (d2 < minv) { minv = d2; mini = k + 2; }
        if (d3 < minv) { minv = d3; mini = k + 3; }
    }

    // ---- gather the winning codebook row: ALL 128 floats (32 float4s) ----
    const float4* src = (const float4*)(eT + (size_t)mini * 128);
    float4* dst = (float4*)(out + ((size_t)(px_base + p)) * 128);
    #pragma unroll
    for (int q = 0; q < 32; ++q) dst[q] = src[q];
}

// ---------------------------------------------------------------------------
extern "C" void kernel_launch(void* const* d_in, const int* in_sizes, int n_in,
                              void* d_out, int out_size, void* d_ws, size_t ws_size,
                              hipStream_t stream) {
    const float* x   = (const float*)d_in[0];
    const float* w1  = (const float*)d_in[1];
    const float* b1  = (const float*)d_in[2];
    const float* w2  = (const float*)d_in[3];
    const float* b2  = (const float*)d_in[4];
    const float* w3  = (const float*)d_in[5];
    const float* b3  = (const float*)d_in[6];
    const float* emb = (const float*)d_in[7];
    float* out = (float*)d_out;

    const size_t H1_FULL = 33554432;   // 64*128*128*32 floats (128 MiB)
    const size_t H2_FULL = 16777216;   // 64*64*64*64   floats ( 64 MiB)
    const size_t FIXEDF  = 65536 + 512;  // eT + cvec

    // smallest power-of-two chunk count whose peak scratch fits ws_size
    // (worst case nchunk=64 needs ~3.4 MiB; clamp there regardless)
    int nchunk = 1;
    while (nchunk < 64 &&
           (FIXEDF + (H1_FULL + H2_FULL) / (size_t)nchunk) * 4 > ws_size)
        nchunk <<= 1;
    int bpc = 64 / nchunk;             // images per chunk

    float* ws = (float*)d_ws;
    float* eT = ws;                    // 65,536 floats
    float* cv = eT + 65536;            // 512 floats
    float* h1 = cv + 512;              // H1_FULL/nchunk floats
    float* h2 = h1 + H1_FULL / (size_t)nchunk;  // H2_FULL/nchunk floats

    k_prep<<<2, 256, 0, stream>>>(emb, eT, cv);
    int nblk = 4096 / nchunk;          // conv blocks per chunk
    int nblk_vq = 1024 / nchunk;       // k_vq: 256 px/block
    for (int ch = 0; ch < nchunk; ++ch) {
        int b0 = ch * bpc;
        k_conv1<<<nblk, 256, 0, stream>>>(x, w1, b1, h1, b0);
        k_conv2<<<nblk, 256, 0, stream>>>(h1, w2, b2, h2);
        k_vq   <<<nblk_vq, 256, 0, stream>>>(h2, w3, b3, eT, cv, out,
                                             (long long)b0 * 4096);
    }
}

// Round 7
// 1671.628 us; speedup vs baseline: 1.0083x; 1.0083x over previous
//
#include <hip/hip_runtime.h>

// ---------------------------------------------------------------------------
// VQ-VAE encoder + vector quantizer, fp32 end-to-end (no MFMA: argmin is a
// discrete decision; bf16 noise would flip indices vs the fp32 reference).
//
//   k_prep : eT[k][d] = emb[d][k];  c[k] = ||e_k||^2
//   k_conv1: 4x4 s2 SAME, 3->32, relu   (weights via wave-uniform s_loads)
//   k_conv2: 4x4 s2 SAME, 32->64, relu  (LDS-tiled implicit GEMM)
//   k_vq   : all-register conv3+VQ (z[128] in VGPRs, codebook via uniform
//            scalar-broadcast loads, no LDS).
//
// r7 FIX vs r6: __launch_bounds__(256,3) capped k_vq at ~168 VGPRs; the
// compiler demoted z[128] to scratch (VGPR_Count=84 proved it: a kernel
// holding z in regs needs >=128). Phase B then did 65K scratch reads per
// thread -> 1231 us, VALUBusy 43%. Now (256,1): no register cap, z stays
// in VGPRs (~200), 2 waves/SIMD. Arithmetic is untouched -> absmax 0.0
// preserved.
//
// Batch-chunked: the 64 images are processed in `nchunk` chunks so the h1/h2
// intermediates fit whatever ws_size the harness provides. Launch schedule is
// a pure function of ws_size -> identical work every call (graph-capture safe).
// ---------------------------------------------------------------------------

__device__ __forceinline__ float fget(const float4& v, int i) {
    return reinterpret_cast<const float*>(&v)[i];
}

// ---- K0: codebook prep --------------------------------------------------
__global__ void k_prep(const float* __restrict__ emb,
                       float* __restrict__ eT, float* __restrict__ cvec) {
    int k = blockIdx.x * 256 + threadIdx.x;   // 512 threads total
    float s = 0.f;
    #pragma unroll 8
    for (int d = 0; d < 128; ++d) {
        float v = emb[d * 512 + k];           // coalesced (consecutive k)
        s += v * v;
        eT[k * 128 + d] = v;
    }
    cvec[k] = s;
}

// ---- K1: conv1 + relu ---------------------------------------------------
// thread = one output pixel, all 32 channels. Weight indices are wave-uniform
// -> compiler emits s_load; weights live in SGPRs, FMAs take SGPR operand.
__global__ __launch_bounds__(256) void k_conv1(
        const float* __restrict__ x, const float* __restrict__ w1,
        const float* __restrict__ b1, float* __restrict__ h1, int b0) {
    int t = threadIdx.x;
    int p = blockIdx.x * 256 + t;             // chunk-local pixel id
    int ow = p & 127, oh = (p >> 7) & 127, b = b0 + (p >> 14);
    float acc[32];
    #pragma unroll
    for (int c = 0; c < 32; ++c) acc[c] = b1[c];     // uniform scalar loads
    #pragma unroll
    for (int kh = 0; kh < 4; ++kh) {
        int ih = oh * 2 - 1 + kh;                    // SAME pad_lo = 1
        if ((unsigned)ih >= 256u) continue;
        #pragma unroll
        for (int kw = 0; kw < 4; ++kw) {
            int iw = ow * 2 - 1 + kw;
            if ((unsigned)iw >= 256u) continue;
            const float* xp = x + (((size_t)(b * 256 + ih) * 256 + iw) * 3);
            float x0 = xp[0], x1 = xp[1], x2 = xp[2];
            const float* wp = w1 + (kh * 4 + kw) * 96;  // [ci][32c], uniform
            #pragma unroll
            for (int c = 0; c < 32; ++c)
                acc[c] += x0 * wp[c] + x1 * wp[32 + c] + x2 * wp[64 + c];
        }
    }
    float4* op = (float4*)(h1 + (size_t)p * 32);  // thread writes 1 cache line
    #pragma unroll
    for (int c4 = 0; c4 < 8; ++c4) {
        float4 v;
        v.x = fmaxf(acc[c4 * 4 + 0], 0.f);
        v.y = fmaxf(acc[c4 * 4 + 1], 0.f);
        v.z = fmaxf(acc[c4 * 4 + 2], 0.f);
        v.w = fmaxf(acc[c4 * 4 + 3], 0.f);
        op[c4] = v;
    }
}

// ---- K2: conv2 + relu (implicit GEMM, LDS-tiled) ------------------------
// block: 8x8 output pixels x 64 ch for one image. x-tile 18x18x32 in LDS
// (row padded to 580 floats -> 4-row stride = 2320 % 32 = 16 -> 2-way, free).
// weights staged per-kh (32KB). thread (tr,tc): tr->4 px (swizzled so in-wave
// groups differ in ROW), tc->4 cout. 64 FMA per 8 ds_read_b128.
#define XROW 580
__global__ __launch_bounds__(256) void k_conv2(
        const float* __restrict__ h1, const float* __restrict__ w2,
        const float* __restrict__ b2, float* __restrict__ h2) {
    __shared__ float xl[18 * XROW];     // 41.76 KB
    __shared__ float wl[8192];          // 32 KB  (one kh slice: [kw][ci][co])
    __shared__ float bl[64];
    int t = threadIdx.x;
    int blk = blockIdx.x;
    int tx = blk & 7, ty = (blk >> 3) & 7, b = blk >> 6;   // b = chunk-local
    int oh0 = ty * 8, ow0 = tx * 8;
    int ih0 = oh0 * 2 - 1, iw0 = ow0 * 2 - 1;
    if (t < 64) bl[t] = b2[t];
    // stage x tile: 18x18 positions x 8 float4 of channels
    for (int i = t; i < 2592; i += 256) {
        int f = i & 7;
        int pos = i >> 3;
        int r = pos / 18, c = pos - r * 18;
        int ih = ih0 + r, iw = iw0 + c;
        float4 v = make_float4(0.f, 0.f, 0.f, 0.f);
        if ((unsigned)ih < 128u && (unsigned)iw < 128u)
            v = *(const float4*)(h1 + ((size_t)((b * 128 + ih) * 128 + iw) * 32 + f * 4));
        *(float4*)(xl + r * XROW + c * 32 + f * 4) = v;
    }
    int tc = t & 15, tr = t >> 4;
    int g = ((tr & 3) << 2) | (tr >> 2);   // in-wave groups span different rows
    int olr = g >> 1, olc0 = (g & 1) * 4;
    __syncthreads();
    float4 bv = ((const float4*)bl)[tc];
    float4 acc[4];
    #pragma unroll
    for (int j = 0; j < 4; ++j) acc[j] = bv;
    for (int kh = 0; kh < 4; ++kh) {
        __syncthreads();                               // prev wl reads done
        const float4* wsrc = (const float4*)(w2 + kh * 8192);
        for (int i = t; i < 2048; i += 256) ((float4*)wl)[i] = wsrc[i];
        __syncthreads();
        #pragma unroll
        for (int kw = 0; kw < 4; ++kw) {
            #pragma unroll
            for (int ci4 = 0; ci4 < 8; ++ci4) {
                float4 xq[4], wq[4];
                #pragma unroll
                for (int j = 0; j < 4; ++j)
                    xq[j] = *(const float4*)(xl + (olr * 2 + kh) * XROW +
                                             ((olc0 + j) * 2 + kw) * 32 + ci4 * 4);
                #pragma unroll
                for (int i = 0; i < 4; ++i)
                    wq[i] = ((const float4*)wl)[(kw * 32 + ci4 * 4 + i) * 16 + tc];
                #pragma unroll
                for (int i = 0; i < 4; ++i) {
                    #pragma unroll
                    for (int j = 0; j < 4; ++j) {
                        float xv = fget(xq[j], i);
                        acc[j].x += xv * wq[i].x;
                        acc[j].y += xv * wq[i].y;
                        acc[j].z += xv * wq[i].z;
                        acc[j].w += xv * wq[i].w;
                    }
                }
            }
        }
    }
    int oh = oh0 + olr;
    #pragma unroll
    for (int j = 0; j < 4; ++j) {
        int ow = ow0 + olc0 + j;
        float4 v = acc[j];
        v.x = fmaxf(v.x, 0.f); v.y = fmaxf(v.y, 0.f);
        v.z = fmaxf(v.z, 0.f); v.w = fmaxf(v.w, 0.f);
        *(float4*)(h2 + ((size_t)((b * 64 + oh) * 64 + ow) * 64 + tc * 4)) = v;
    }
}

// ---- K3: conv3(1x1) + VQ argmin + gather, all-register ------------------
// thread = 1 pixel. z[128] in VGPRs; w3/b3/eT/cvec read with wave-uniform
// indices -> scalar (SGPR-broadcast) loads; FMAs are v_fmac_f32 with one
// SGPR operand. No LDS.
//   z[d]  = b3[d] + sum_{ci ascending} h[ci]*w3[ci][d]     (one fma chain)
//   s_k   = sum_{d ascending} z[d]*eT[k][d]                (one fma chain)
//   dist  = cvec[k] - 2.f*s_k        (||z||^2 constant, drops under argmin)
// Selection: ascending-k strict '<' = global first-min (jnp.argmin).
// __launch_bounds__(256, 1): NO register cap (r6's (256,3) cap demoted
// z[128] to scratch -> VGPR_Count 84, 65K scratch reads/thread, 1231 us).
__global__ __launch_bounds__(256, 1) void k_vq(
        const float* __restrict__ h2, const float* __restrict__ w3,
        const float* __restrict__ b3, const float* __restrict__ eT,
        const float* __restrict__ cvec, float* __restrict__ out,
        long long px_base) {
    int p = blockIdx.x * 256 + threadIdx.x;   // chunk-local pixel
    const float* h2row = h2 + (size_t)p * 64;

    // ---- phase A: z = w3^T . h2row + b3 (z stays in registers) ----
    float z[128];
    #pragma unroll
    for (int d = 0; d < 128; ++d) z[d] = b3[d];        // uniform -> s_load
    for (int ci = 0; ci < 64; ci += 4) {
        float4 hv = *(const float4*)(h2row + ci);      // per-thread load
        const float* w0 = w3 + ci * 128;
        #pragma unroll
        for (int j = 0; j < 4; ++j) {
            float h = fget(hv, j);
            const float* wr = w0 + j * 128;            // uniform row
            #pragma unroll
            for (int d = 0; d < 128; ++d) z[d] += h * wr[d];
        }
    }

    // ---- phase B: argmin_k ( ||e_k||^2 - 2 z.e_k ) ----
    // ILP across 4 independent codes; each code's dot is ONE ascending chain.
    float minv = 3.4e38f;
    int mini = 0;
    for (int k = 0; k < 512; k += 4) {
        const float* e0 = eT + (size_t)k * 128;        // uniform rows
        const float* e1 = e0 + 128;
        const float* e2 = e0 + 256;
        const float* e3 = e0 + 384;
        float s0 = 0.f, s1 = 0.f, s2 = 0.f, s3 = 0.f;
        #pragma unroll
        for (int d = 0; d < 128; ++d) {
            s0 += z[d] * e0[d];
            s1 += z[d] * e1[d];
            s2 += z[d] * e2[d];
            s3 += z[d] * e3[d];
        }
        float d0 = cvec[k + 0] - 2.f * s0;
        float d1 = cvec[k + 1] - 2.f * s1;
        float d2 = cvec[k + 2] - 2.f * s2;
        float d3 = cvec[k + 3] - 2.f * s3;
        if (d0 < minv) { minv = d0; mini = k + 0; }
        if (d1 < minv) { minv = d1; mini = k + 1; }
        if (d2 < minv) { minv = d2; mini = k + 2; }
        if (d3 < minv) { minv = d3; mini = k + 3; }
    }

    // ---- gather the winning codebook row: ALL 128 floats (32 float4s) ----
    const float4* src = (const float4*)(eT + (size_t)mini * 128);
    float4* dst = (float4*)(out + ((size_t)(px_base + p)) * 128);
    #pragma unroll
    for (int q = 0; q < 32; ++q) dst[q] = src[q];
}

// ---------------------------------------------------------------------------
extern "C" void kernel_launch(void* const* d_in, const int* in_sizes, int n_in,
                              void* d_out, int out_size, void* d_ws, size_t ws_size,
                              hipStream_t stream) {
    const float* x   = (const float*)d_in[0];
    const float* w1  = (const float*)d_in[1];
    const float* b1  = (const float*)d_in[2];
    const float* w2  = (const float*)d_in[3];
    const float* b2  = (const float*)d_in[4];
    const float* w3  = (const float*)d_in[5];
    const float* b3  = (const float*)d_in[6];
    const float* emb = (const float*)d_in[7];
    float* out = (float*)d_out;

    const size_t H1_FULL = 33554432;   // 64*128*128*32 floats (128 MiB)
    const size_t H2_FULL = 16777216;   // 64*64*64*64   floats ( 64 MiB)
    const size_t FIXEDF  = 65536 + 512;  // eT + cvec

    // smallest power-of-two chunk count whose peak scratch fits ws_size
    // (worst case nchunk=64 needs ~3.4 MiB; clamp there regardless)
    int nchunk = 1;
    while (nchunk < 64 &&
           (FIXEDF + (H1_FULL + H2_FULL) / (size_t)nchunk) * 4 > ws_size)
        nchunk <<= 1;
    int bpc = 64 / nchunk;             // images per chunk

    float* ws = (float*)d_ws;
    float* eT = ws;                    // 65,536 floats
    float* cv = eT + 65536;            // 512 floats
    float* h1 = cv + 512;              // H1_FULL/nchunk floats
    float* h2 = h1 + H1_FULL / (size_t)nchunk;  // H2_FULL/nchunk floats

    k_prep<<<2, 256, 0, stream>>>(emb, eT, cv);
    int nblk = 4096 / nchunk;          // conv blocks per chunk
    int nblk_vq = 1024 / nchunk;       // k_vq: 256 px/block
    for (int ch = 0; ch < nchunk; ++ch) {
        int b0 = ch * bpc;
        k_conv1<<<nblk, 256, 0, stream>>>(x, w1, b1, h1, b0);
        k_conv2<<<nblk, 256, 0, stream>>>(h1, w2, b2, h2);
        k_vq   <<<nblk_vq, 256, 0, stream>>>(h2, w3, b3, eT, cv, out,
                                             (long long)b0 * 4096);
    }
}